// Round 10
// baseline (72.729 us; speedup 1.0000x reference)
//
#include <hip/hip_runtime.h>
#include <hip/hip_bf16.h>
#include <math.h>

// Causal self-attention fwd, B=2 H=16 T=2048 D=64, fp32 in/out.
// Pre-pass: K and V -> bf16 MFMA-fragment-ordered images per 64x64 tile
// (fragment f's lane l at base + f*1024 + l*16 -> 1KB coalesced wave loads).
// Main: 2048 blocks x 128 threads. Block = one 32-row q-tile; wave0 takes
// EVEN k-tiles, wave1 ODD (split-k) -> max wave length 16 iters, 4096 waves
// (4/SIMD, VGPR<=128). Partials combined via 8KB LDS, one barrier.
// Octave-reflected p-mapping makes every CU stripe exactly 132 tile-iters.
// 32x32x16 MFMA, swapped QK^T, bare exp2 softmax (Q pre-scaled), P in
// registers via v_cvt_pk_bf16_f32 + v_permlane32_swap_b32.

#define BATCH 2
#define HEADS 16
#define SEQ   2048
#define DIM   64
#define NBH   (BATCH * HEADS)          // 32
#define NKT_G (SEQ / 64)               // 32 tiles per (b,h)
#define TILE_SHORTS 4096               // 64x64 bf16 tile (8KB)

typedef __attribute__((ext_vector_type(8)))  short    bf16x8;
typedef __attribute__((ext_vector_type(4)))  unsigned u32x4;
typedef __attribute__((ext_vector_type(4)))  float    f32x4;
typedef __attribute__((ext_vector_type(16))) float    f32x16;

__device__ inline short f2bf(float f) {
    unsigned u = __builtin_bit_cast(unsigned, f);
    u += 0x7fff + ((u >> 16) & 1);      // round-to-nearest-even
    return (short)(u >> 16);
}

__device__ inline unsigned cvtpk(float a, float b) {   // low16 = a, high16 = b
    unsigned r;
    asm("v_cvt_pk_bf16_f32 %0, %1, %2" : "=v"(r) : "v"(a), "v"(b));
    return r;
}

// ---- pre-pass: one block per (bh, kt) 64x64 tile ----
// K frag (kb,ds): lane l holds K[kb*32 + (l&31)][ds*16 + (l>>5)*8 + j]
// V frag (db,s):  lane l holds V[s*16 + (l>>5)*8 + j][db*32 + (l&31)]
__global__ __launch_bounds__(256)
void prep_kv(const float* __restrict__ K, const float* __restrict__ V,
             short* __restrict__ Kimg, short* __restrict__ Vimg) {
    const int tile = blockIdx.x;                 // (bh*32 + kt), 0..1023
    const int tid  = threadIdx.x;
    const float* Ksrc = K + (size_t)tile * TILE_SHORTS;
    const float* Vsrc = V + (size_t)tile * TILE_SHORTS;
    char* Kdst = (char*)(Kimg + (size_t)tile * TILE_SHORTS);
    char* Vdst = (char*)(Vimg + (size_t)tile * TILE_SHORTS);

    __shared__ float vt[64][65];

    {   // stage V rows -> LDS fp32 (coalesced reads)
        const int r  = tid >> 2;
        const int c0 = (tid & 3) * 16;
        #pragma unroll
        for (int j = 0; j < 16; j += 4) {
            const f32x4 v = *reinterpret_cast<const f32x4*>(Vsrc + (size_t)r * 64 + c0 + j);
            vt[r][c0+j] = v[0]; vt[r][c0+j+1] = v[1]; vt[r][c0+j+2] = v[2]; vt[r][c0+j+3] = v[3];
        }
    }

    const int f = tid >> 6;                      // 0..3 (ds or s)
    const int l = tid & 63;
    const int l31 = l & 31;
    const int l8  = (l >> 5) * 8;

    #pragma unroll
    for (int kb = 0; kb < 2; ++kb) {
        const float* src = Ksrc + (size_t)(kb * 32 + l31) * 64 + f * 16 + l8;
        const f32x4 a = *reinterpret_cast<const f32x4*>(src);
        const f32x4 b = *reinterpret_cast<const f32x4*>(src + 4);
        short h[8];
        #pragma unroll
        for (int j = 0; j < 4; ++j) { h[j] = f2bf(a[j]); h[4+j] = f2bf(b[j]); }
        *reinterpret_cast<bf16x8*>(Kdst + ((kb * 4 + f) * 64 + l) * 16) =
            *reinterpret_cast<bf16x8*>(h);
    }

    __syncthreads();

    #pragma unroll
    for (int db = 0; db < 2; ++db) {
        const int d  = db * 32 + l31;
        const int k0 = f * 16 + l8;
        short h[8];
        #pragma unroll
        for (int j = 0; j < 8; ++j) h[j] = f2bf(vt[k0 + j][d]);
        *reinterpret_cast<bf16x8*>(Vdst + ((db * 4 + f) * 64 + l) * 16) =
            *reinterpret_cast<bf16x8*>(h);
    }
}

__global__ __launch_bounds__(128, 4)
void fa_fwd(const float* __restrict__ Q, const short* __restrict__ Kimg,
            const short* __restrict__ Vimg, float* __restrict__ O) {
    const int tid  = threadIdx.x;
    const int lane = tid & 63;
    const int wid  = tid >> 6;                   // 0,1 : even/odd k-tiles
    const int q31  = lane & 31;
    const int hi2  = lane >> 5;                  // 0,1

    // bh = idx&31 -> CU-local images; octave-reflected p-map balances stripes
    const int idx = blockIdx.x;                  // 0..2047
    const int bh  = idx & 31;
    const int j   = idx >> 5;                    // 0..63
    const int k8  = j >> 3;
    const int g8  = j & 7;
    const int p   = (k8 & 1) ? (k8 * 8 + 7 - g8) : j;   // 32-row q-tile index
    const int qw  = p * 32;                      // first q row
    const int kd  = p >> 1;                      // diagonal 64-k-tile index
    const int qrel = (p & 1) * 32 + q31;         // mask threshold on diag tile

    const float* Qb = Q + (size_t)bh * SEQ * DIM;
    float*       Ob = O + (size_t)bh * SEQ * DIM;
    const char*  Ktb = (const char*)(Kimg + (size_t)bh * NKT_G * TILE_SHORTS);
    const char*  Vtb = (const char*)(Vimg + (size_t)bh * NKT_G * TILE_SHORTS);
    const unsigned lb = (unsigned)lane * 16;     // lane byte offset in a frag

    __shared__ float accL[32][64];               // 8KB partial-O combine
    __shared__ float rsL[32];

    // ---- Q B-frags, pre-scaled by 0.125*log2(e): col=q=q31, k(d)=hi2*8+j ----
    const float SCL = 0.18033688011112042f;
    bf16x8 qf[4];
    #pragma unroll
    for (int ds = 0; ds < 4; ++ds) {
        const float* src = Qb + (size_t)(qw + q31) * DIM + ds * 16 + hi2 * 8;
        const f32x4 a = *reinterpret_cast<const f32x4*>(src);
        const f32x4 b = *reinterpret_cast<const f32x4*>(src + 4);
        bf16x8 q;
        #pragma unroll
        for (int jj = 0; jj < 4; ++jj) {
            q[jj]     = f2bf(a[jj] * SCL);
            q[4 + jj] = f2bf(b[jj] * SCL);
        }
        qf[ds] = q;
    }

    f32x16 acc0 = {}, acc1 = {};                 // partial O[32q][d 0-31 | 32-63]
    float rs = 0.f;

    for (int kt = wid; kt <= kd; kt += 2) {      // split-k: parity-owned tiles
        const char* Kt = Ktb + (size_t)kt * 8192;
        const char* Vt = Vtb + (size_t)kt * 8192;

        // ---- 16 coalesced 1KB fragment loads ----
        bf16x8 kf[2][4], vf[2][4];
        #pragma unroll
        for (int kb = 0; kb < 2; ++kb)
            #pragma unroll
            for (int ds = 0; ds < 4; ++ds)
                kf[kb][ds] = *reinterpret_cast<const bf16x8*>(
                    Kt + (kb * 4 + ds) * 1024 + lb);
        #pragma unroll
        for (int db = 0; db < 2; ++db)
            #pragma unroll
            for (int s = 0; s < 4; ++s)
                vf[db][s] = *reinterpret_cast<const bf16x8*>(
                    Vt + (db * 4 + s) * 1024 + lb);

        // ---- S^T = K Q^T ----
        f32x16 st0 = {}, st1 = {};
        __builtin_amdgcn_s_setprio(1);
        #pragma unroll
        for (int ds = 0; ds < 4; ++ds)
            st0 = __builtin_amdgcn_mfma_f32_32x32x16_bf16(kf[0][ds], qf[ds], st0, 0, 0, 0);
        #pragma unroll
        for (int ds = 0; ds < 4; ++ds)
            st1 = __builtin_amdgcn_mfma_f32_32x32x16_bf16(kf[1][ds], qf[ds], st1, 0, 0, 0);
        __builtin_amdgcn_s_setprio(0);

        // ---- bare-exp2 softmax; mask only on the diagonal tile ----
        const bool lastt = (kt == kd);
        float p0[16], p1[16];
        #pragma unroll
        for (int r = 0; r < 16; ++r) {
            const int kloc = (r & 3) + 8 * (r >> 2) + 4 * hi2;
            float v0 = __builtin_amdgcn_exp2f(st0[r]);
            float v1 = __builtin_amdgcn_exp2f(st1[r]);
            if (lastt) {
                if (kloc > qrel)      v0 = 0.f;
                if (kloc + 32 > qrel) v1 = 0.f;
            }
            p0[r] = v0; p1[r] = v1;
            rs += v0 + v1;
        }

        // ---- P -> bf16 A-frags in-register (cvt_pk + permlane32_swap) ----
        __builtin_amdgcn_s_setprio(1);
        #pragma unroll
        for (int s = 0; s < 4; ++s) {
            const float* pk = (s >> 1) ? p1 : p0;
            const int u = (s & 1) * 8;
            unsigned Xa = cvtpk(pk[u],     pk[u + 1]);
            unsigned Ya = cvtpk(pk[u + 2], pk[u + 3]);
            unsigned Xb = cvtpk(pk[u + 4], pk[u + 5]);
            unsigned Yb = cvtpk(pk[u + 6], pk[u + 7]);
            asm("v_permlane32_swap_b32 %0, %1" : "+v"(Xa), "+v"(Xb));
            asm("v_permlane32_swap_b32 %0, %1" : "+v"(Ya), "+v"(Yb));
            const u32x4 w = {Xa, Ya, Xb, Yb};
            const bf16x8 pa = __builtin_bit_cast(bf16x8, w);
            acc0 = __builtin_amdgcn_mfma_f32_32x32x16_bf16(pa, vf[0][s], acc0, 0, 0, 0);
            acc1 = __builtin_amdgcn_mfma_f32_32x32x16_bf16(pa, vf[1][s], acc1, 0, 0, 0);
        }
        __builtin_amdgcn_s_setprio(0);
    }

    // ---- combine the two waves' partials via LDS ----
    rs += __shfl_xor(rs, 32, 64);                // both k-halves within wave

    if (wid == 0) {
        #pragma unroll
        for (int r = 0; r < 16; ++r) {
            const int off = (r & 3) + 8 * (r >> 2) + 4 * hi2;
            accL[off][q31]      = acc0[r];
            accL[off][q31 + 32] = acc1[r];
        }
        if (lane < 32) rsL[lane] = rs;           // hi2==0 lanes, q31==lane
    }
    __syncthreads();

    if (wid == 1) {
        const float rstot = rs + rsL[q31];
        const float inv = 1.0f / rstot;
        #pragma unroll
        for (int r = 0; r < 16; ++r) {
            const int off = (r & 3) + 8 * (r >> 2) + 4 * hi2;
            const float ir = __shfl(inv, off, 64);
            const float o0 = acc0[r] + accL[off][q31];
            const float o1 = acc1[r] + accL[off][q31 + 32];
            float* dst = Ob + (size_t)(qw + off) * DIM + q31;
            dst[0]  = o0 * ir;
            dst[32] = o1 * ir;
        }
    }
}

extern "C" void kernel_launch(void* const* d_in, const int* in_sizes, int n_in,
                              void* d_out, int out_size, void* d_ws, size_t ws_size,
                              hipStream_t stream) {
    const float* Q = (const float*)d_in[0];
    const float* K = (const float*)d_in[1];
    const float* V = (const float*)d_in[2];
    float*       O = (float*)d_out;

    short* Kimg = (short*)d_ws;                                        // 8 MiB
    short* Vimg = (short*)d_ws + (size_t)NBH * NKT_G * TILE_SHORTS;    // 8 MiB

    prep_kv<<<dim3(NBH * NKT_G), dim3(256), 0, stream>>>(K, V, Kimg, Vimg);
    fa_fwd<<<dim3(NBH * 64), dim3(128), 0, stream>>>(Q, Kimg, Vimg, O);
}

// Round 11
// 49.038 us; speedup vs baseline: 1.4831x; 1.4831x over previous
//
#include <hip/hip_runtime.h>
#include <hip/hip_bf16.h>
#include <math.h>

// Causal self-attention fwd, B=2 H=16 T=2048 D=64, fp32 in/out.
// Pre-pass: K and V -> bf16 MFMA-fragment-ordered images per 64x64 tile
// (fragment f's lane l at base + f*1024 + l*16 -> 1KB coalesced wave loads).
// Main: 2048 blocks x 128 threads. Block = one 32-row q-tile; wave0 takes
// EVEN k-tiles, wave1 ODD (split-k) -> max wave length 16 iters, 4096 waves.
// NO min-waves launch bound (R10's (128,4) forced 64 VGPR -> scratch spills,
// WRITE_SIZE 62MB; natural allocation ~90 VGPR keeps 4 waves/SIMD capacity).
// Partials combined via 8KB LDS, one barrier. Octave-reflected p-mapping
// makes every CU stripe exactly 252 tile-iters. 32x32x16 MFMA, swapped QK^T,
// bare exp2 softmax (Q pre-scaled), P in registers via v_cvt_pk_bf16_f32 +
// v_permlane32_swap_b32.

#define BATCH 2
#define HEADS 16
#define SEQ   2048
#define DIM   64
#define NBH   (BATCH * HEADS)          // 32
#define NKT_G (SEQ / 64)               // 32 tiles per (b,h)
#define TILE_SHORTS 4096               // 64x64 bf16 tile (8KB)

typedef __attribute__((ext_vector_type(8)))  short    bf16x8;
typedef __attribute__((ext_vector_type(4)))  unsigned u32x4;
typedef __attribute__((ext_vector_type(4)))  float    f32x4;
typedef __attribute__((ext_vector_type(16))) float    f32x16;

__device__ inline short f2bf(float f) {
    unsigned u = __builtin_bit_cast(unsigned, f);
    u += 0x7fff + ((u >> 16) & 1);      // round-to-nearest-even
    return (short)(u >> 16);
}

__device__ inline unsigned cvtpk(float a, float b) {   // low16 = a, high16 = b
    unsigned r;
    asm("v_cvt_pk_bf16_f32 %0, %1, %2" : "=v"(r) : "v"(a), "v"(b));
    return r;
}

// ---- pre-pass: one block per (bh, kt) 64x64 tile ----
// K frag (kb,ds): lane l holds K[kb*32 + (l&31)][ds*16 + (l>>5)*8 + j]
// V frag (db,s):  lane l holds V[s*16 + (l>>5)*8 + j][db*32 + (l&31)]
__global__ __launch_bounds__(256)
void prep_kv(const float* __restrict__ K, const float* __restrict__ V,
             short* __restrict__ Kimg, short* __restrict__ Vimg) {
    const int tile = blockIdx.x;                 // (bh*32 + kt), 0..1023
    const int tid  = threadIdx.x;
    const float* Ksrc = K + (size_t)tile * TILE_SHORTS;
    const float* Vsrc = V + (size_t)tile * TILE_SHORTS;
    char* Kdst = (char*)(Kimg + (size_t)tile * TILE_SHORTS);
    char* Vdst = (char*)(Vimg + (size_t)tile * TILE_SHORTS);

    __shared__ float vt[64][65];

    {   // stage V rows -> LDS fp32 (coalesced reads)
        const int r  = tid >> 2;
        const int c0 = (tid & 3) * 16;
        #pragma unroll
        for (int j = 0; j < 16; j += 4) {
            const f32x4 v = *reinterpret_cast<const f32x4*>(Vsrc + (size_t)r * 64 + c0 + j);
            vt[r][c0+j] = v[0]; vt[r][c0+j+1] = v[1]; vt[r][c0+j+2] = v[2]; vt[r][c0+j+3] = v[3];
        }
    }

    const int f = tid >> 6;                      // 0..3 (ds or s)
    const int l = tid & 63;
    const int l31 = l & 31;
    const int l8  = (l >> 5) * 8;

    #pragma unroll
    for (int kb = 0; kb < 2; ++kb) {
        const float* src = Ksrc + (size_t)(kb * 32 + l31) * 64 + f * 16 + l8;
        const f32x4 a = *reinterpret_cast<const f32x4*>(src);
        const f32x4 b = *reinterpret_cast<const f32x4*>(src + 4);
        short h[8];
        #pragma unroll
        for (int j = 0; j < 4; ++j) { h[j] = f2bf(a[j]); h[4+j] = f2bf(b[j]); }
        *reinterpret_cast<bf16x8*>(Kdst + ((kb * 4 + f) * 64 + l) * 16) =
            *reinterpret_cast<bf16x8*>(h);
    }

    __syncthreads();

    #pragma unroll
    for (int db = 0; db < 2; ++db) {
        const int d  = db * 32 + l31;
        const int k0 = f * 16 + l8;
        short h[8];
        #pragma unroll
        for (int j = 0; j < 8; ++j) h[j] = f2bf(vt[k0 + j][d]);
        *reinterpret_cast<bf16x8*>(Vdst + ((db * 4 + f) * 64 + l) * 16) =
            *reinterpret_cast<bf16x8*>(h);
    }
}

__global__ __launch_bounds__(128)
void fa_fwd(const float* __restrict__ Q, const short* __restrict__ Kimg,
            const short* __restrict__ Vimg, float* __restrict__ O) {
    const int tid  = threadIdx.x;
    const int lane = tid & 63;
    const int wid  = tid >> 6;                   // 0,1 : even/odd k-tiles
    const int q31  = lane & 31;
    const int hi2  = lane >> 5;                  // 0,1

    // bh = idx&31 -> CU-local images; octave-reflected p-map balances stripes
    const int idx = blockIdx.x;                  // 0..2047
    const int bh  = idx & 31;
    const int j   = idx >> 5;                    // 0..63
    const int k8  = j >> 3;
    const int g8  = j & 7;
    const int p   = (k8 & 1) ? (k8 * 8 + 7 - g8) : j;   // 32-row q-tile index
    const int qw  = p * 32;                      // first q row
    const int kd  = p >> 1;                      // diagonal 64-k-tile index
    const int qrel = (p & 1) * 32 + q31;         // mask threshold on diag tile

    const float* Qb = Q + (size_t)bh * SEQ * DIM;
    float*       Ob = O + (size_t)bh * SEQ * DIM;
    const char*  Ktb = (const char*)(Kimg + (size_t)bh * NKT_G * TILE_SHORTS);
    const char*  Vtb = (const char*)(Vimg + (size_t)bh * NKT_G * TILE_SHORTS);
    const unsigned lb = (unsigned)lane * 16;     // lane byte offset in a frag

    __shared__ float accL[32][64];               // 8KB partial-O combine
    __shared__ float rsL[32];

    // ---- Q B-frags, pre-scaled by 0.125*log2(e): col=q=q31, k(d)=hi2*8+j ----
    const float SCL = 0.18033688011112042f;
    bf16x8 qf[4];
    #pragma unroll
    for (int ds = 0; ds < 4; ++ds) {
        const float* src = Qb + (size_t)(qw + q31) * DIM + ds * 16 + hi2 * 8;
        const f32x4 a = *reinterpret_cast<const f32x4*>(src);
        const f32x4 b = *reinterpret_cast<const f32x4*>(src + 4);
        bf16x8 q;
        #pragma unroll
        for (int jj = 0; jj < 4; ++jj) {
            q[jj]     = f2bf(a[jj] * SCL);
            q[4 + jj] = f2bf(b[jj] * SCL);
        }
        qf[ds] = q;
    }

    f32x16 acc0 = {}, acc1 = {};                 // partial O[32q][d 0-31 | 32-63]
    float rs = 0.f;

    for (int kt = wid; kt <= kd; kt += 2) {      // split-k: parity-owned tiles
        const char* Kt = Ktb + (size_t)kt * 8192;
        const char* Vt = Vtb + (size_t)kt * 8192;

        // ---- 16 coalesced 1KB fragment loads ----
        bf16x8 kf[2][4], vf[2][4];
        #pragma unroll
        for (int kb = 0; kb < 2; ++kb)
            #pragma unroll
            for (int ds = 0; ds < 4; ++ds)
                kf[kb][ds] = *reinterpret_cast<const bf16x8*>(
                    Kt + (kb * 4 + ds) * 1024 + lb);
        #pragma unroll
        for (int db = 0; db < 2; ++db)
            #pragma unroll
            for (int s = 0; s < 4; ++s)
                vf[db][s] = *reinterpret_cast<const bf16x8*>(
                    Vt + (db * 4 + s) * 1024 + lb);

        // ---- S^T = K Q^T ----
        f32x16 st0 = {}, st1 = {};
        __builtin_amdgcn_s_setprio(1);
        #pragma unroll
        for (int ds = 0; ds < 4; ++ds)
            st0 = __builtin_amdgcn_mfma_f32_32x32x16_bf16(kf[0][ds], qf[ds], st0, 0, 0, 0);
        #pragma unroll
        for (int ds = 0; ds < 4; ++ds)
            st1 = __builtin_amdgcn_mfma_f32_32x32x16_bf16(kf[1][ds], qf[ds], st1, 0, 0, 0);
        __builtin_amdgcn_s_setprio(0);

        // ---- bare-exp2 softmax; mask only on the diagonal tile ----
        const bool lastt = (kt == kd);
        float p0[16], p1[16];
        #pragma unroll
        for (int r = 0; r < 16; ++r) {
            const int kloc = (r & 3) + 8 * (r >> 2) + 4 * hi2;
            float v0 = __builtin_amdgcn_exp2f(st0[r]);
            float v1 = __builtin_amdgcn_exp2f(st1[r]);
            if (lastt) {
                if (kloc > qrel)      v0 = 0.f;
                if (kloc + 32 > qrel) v1 = 0.f;
            }
            p0[r] = v0; p1[r] = v1;
            rs += v0 + v1;
        }

        // ---- P -> bf16 A-frags in-register (cvt_pk + permlane32_swap) ----
        __builtin_amdgcn_s_setprio(1);
        #pragma unroll
        for (int s = 0; s < 4; ++s) {
            const float* pk = (s >> 1) ? p1 : p0;
            const int u = (s & 1) * 8;
            unsigned Xa = cvtpk(pk[u],     pk[u + 1]);
            unsigned Ya = cvtpk(pk[u + 2], pk[u + 3]);
            unsigned Xb = cvtpk(pk[u + 4], pk[u + 5]);
            unsigned Yb = cvtpk(pk[u + 6], pk[u + 7]);
            asm("v_permlane32_swap_b32 %0, %1" : "+v"(Xa), "+v"(Xb));
            asm("v_permlane32_swap_b32 %0, %1" : "+v"(Ya), "+v"(Yb));
            const u32x4 w = {Xa, Ya, Xb, Yb};
            const bf16x8 pa = __builtin_bit_cast(bf16x8, w);
            acc0 = __builtin_amdgcn_mfma_f32_32x32x16_bf16(pa, vf[0][s], acc0, 0, 0, 0);
            acc1 = __builtin_amdgcn_mfma_f32_32x32x16_bf16(pa, vf[1][s], acc1, 0, 0, 0);
        }
        __builtin_amdgcn_s_setprio(0);
    }

    // ---- combine the two waves' partials via LDS ----
    rs += __shfl_xor(rs, 32, 64);                // both k-halves within wave

    if (wid == 0) {
        #pragma unroll
        for (int r = 0; r < 16; ++r) {
            const int off = (r & 3) + 8 * (r >> 2) + 4 * hi2;
            accL[off][q31]      = acc0[r];
            accL[off][q31 + 32] = acc1[r];
        }
        if (lane < 32) rsL[lane] = rs;           // hi2==0 lanes, q31==lane
    }
    __syncthreads();

    if (wid == 1) {
        const float rstot = rs + rsL[q31];
        const float inv = 1.0f / rstot;
        #pragma unroll
        for (int r = 0; r < 16; ++r) {
            const int off = (r & 3) + 8 * (r >> 2) + 4 * hi2;
            const float ir = __shfl(inv, off, 64);
            const float o0 = acc0[r] + accL[off][q31];
            const float o1 = acc1[r] + accL[off][q31 + 32];
            float* dst = Ob + (size_t)(qw + off) * DIM + q31;
            dst[0]  = o0 * ir;
            dst[32] = o1 * ir;
        }
    }
}

extern "C" void kernel_launch(void* const* d_in, const int* in_sizes, int n_in,
                              void* d_out, int out_size, void* d_ws, size_t ws_size,
                              hipStream_t stream) {
    const float* Q = (const float*)d_in[0];
    const float* K = (const float*)d_in[1];
    const float* V = (const float*)d_in[2];
    float*       O = (float*)d_out;

    short* Kimg = (short*)d_ws;                                        // 8 MiB
    short* Vimg = (short*)d_ws + (size_t)NBH * NKT_G * TILE_SHORTS;    // 8 MiB

    prep_kv<<<dim3(NBH * NKT_G), dim3(256), 0, stream>>>(K, V, Kimg, Vimg);
    fa_fwd<<<dim3(NBH * 64), dim3(128), 0, stream>>>(Q, Kimg, Vimg, O);
}